// Round 10
// baseline (545.617 us; speedup 1.0000x reference)
//
#include <hip/hip_runtime.h>
#include <hip/hip_bf16.h>
#include <math.h>

#define N_ROWS 65536
#define P_DIM  256
#define C_DIM  3
#define U_DIM  512
#define NPLANES 7
#define PLANE_STRIDE (U_DIM * P_DIM)   // 131072 elements per bf16 plane

#define BM 128
#define BU 64
#define NUT (U_DIM / BU)               // 8 u-tiles, persistent per block

typedef __attribute__((ext_vector_type(8))) short short8;     // 8 bf16 = 4 VGPR
typedef __attribute__((ext_vector_type(4))) float f32x4;
typedef __attribute__((ext_vector_type(4))) float floatx4;
typedef __attribute__((ext_vector_type(4))) unsigned int uint4v;

static __device__ __forceinline__ unsigned short f2bf(float f) {
    unsigned int u = __builtin_bit_cast(unsigned int, f);
    u += 0x7FFFu + ((u >> 16) & 1u);      // RNE
    return (unsigned short)(u >> 16);
}

// E[relu(N(m, v))]; exact relu when v == 0.
// Single-instruction rsq/rcp (1 ulp), Phi via Zelen-Severo poly reusing g = phi(w):
//   s*(g + w*Phi) = s*g + m*Phi ;  Phi(|w|) = 1 - g*poly(t), t = 1/(1+0.2316419|w|)
static __device__ __forceinline__ float erl(float m, float v) {
    float r = __builtin_amdgcn_rsqf(fmaxf(v, 1e-20f));
    float w = m * r;
    float s = v * r;
    float g = __expf(-0.5f * w * w) * 0.3989422804014327f;       // phi(w), even in w
    float aw = fabsf(w);
    float t = __builtin_amdgcn_rcpf(fmaf(0.2316419f, aw, 1.0f));
    float poly = t * (0.319381530f + t * (-0.356563782f + t * (1.781477937f
               + t * (-1.821255978f + t * 1.330274429f))));
    float Phi_pos = 1.0f - g * poly;
    float phi = (w >= 0.0f) ? Phi_pos : 1.0f - Phi_pos;
    float val = s * g + m * phi;
    return (v > 0.0f) ? val : fmaxf(m, 0.0f);
}

// ---------------- prep: build B planes (bf16, [plane][u][k] k-contiguous) + q-tables ----
// plane 0      : kernel[k][u]
// plane 1+c    : mu[k][c]   * kernel[k][u]
// plane 4+c    : var[k][c]  * kernel[k][u]^2
// qtab[p] = 3 float4: a_c = 1/(2v), b_c = -2 m a, d_c = m^2 a + 0.5 log(2 pi v)
__global__ __launch_bounds__(512) void prep_kernel(
    const float* __restrict__ cmeans, const float* __restrict__ cvars,
    const float* __restrict__ kern, unsigned short* __restrict__ Bt,
    float* __restrict__ qtab)
{
    int tid = blockIdx.x * 512 + threadIdx.x;
    const int TOTAL_B = NPLANES * PLANE_STRIDE;   // 917504
    if (tid < TOTAL_B) {
        int pl  = tid >> 17;
        int rem = tid & (PLANE_STRIDE - 1);
        int u   = rem >> 8;
        int k   = rem & (P_DIM - 1);
        float kv = kern[k * U_DIM + u];
        float val;
        if (pl == 0)      val = kv;
        else if (pl <= 3) val = cmeans[k * C_DIM + (pl - 1)] * kv;
        else              val = cvars[k * C_DIM + (pl - 4)] * (kv * kv);
        Bt[tid] = f2bf(val);
    } else if (tid - TOTAL_B < P_DIM) {
        int p = tid - TOTAL_B;
        float a[3], b[3], d[3];
#pragma unroll
        for (int c = 0; c < 3; ++c) {
            float m = cmeans[p * 3 + c];
            float v = cvars[p * 3 + c];
            float iv = 0.5f / v;
            a[c] = iv;
            b[c] = -2.0f * m * iv;
            d[c] = m * m * iv + 0.5f * logf(2.0f * 3.14159265359f * v);
        }
        float* q = qtab + p * 12;
        q[0] = a[0]; q[1] = a[1]; q[2]  = a[2]; q[3]  = 0.f;
        q[4] = b[0]; q[5] = b[1]; q[6]  = b[2]; q[7]  = 0.f;
        q[8] = d[0]; q[9] = d[1]; q[10] = d[2]; q[11] = 0.f;
    }
}

// ---- pass A: planes 0..3 (mean) ----
#define LOADB_M(dst, ksi) do {                                                \
    const unsigned short* _b = bp + (ksi) * 32;                               \
    _Pragma("unroll")                                                         \
    for (int pl = 0; pl < 4; ++pl)                                            \
        dst[pl] = *(const short8*)(_b + (size_t)pl * PLANE_STRIDE);           \
} while (0)

#define STEP_M(breg, ksi) do {                                                \
    __builtin_amdgcn_s_setprio(1);                                            \
    _Pragma("unroll")                                                         \
    for (int r = 0; r < 2; ++r) {                                             \
        short8 a0 = *(const short8*)&xs[aBase + r * 4096 + (ksi) * 512];      \
        short8 a1 = *(const short8*)&mk[aBase + r * 4096 + (ksi) * 512];      \
        acc[0][r] = __builtin_amdgcn_mfma_f32_16x16x32_bf16(a0, breg[0], acc[0][r], 0, 0, 0); \
        _Pragma("unroll")                                                     \
        for (int pl = 1; pl < 4; ++pl)                                        \
            acc[pl][r] = __builtin_amdgcn_mfma_f32_16x16x32_bf16(a1, breg[pl], acc[pl][r], 0, 0, 0); \
    }                                                                         \
    __builtin_amdgcn_s_setprio(0);                                            \
} while (0)

// ---- pass B: planes 4..6 (var) ----
#define LOADB_V(dst, ksi) do {                                                \
    const unsigned short* _b = bp + (ksi) * 32;                               \
    _Pragma("unroll")                                                         \
    for (int j = 0; j < 3; ++j)                                               \
        dst[j] = *(const short8*)(_b + (size_t)(4 + j) * PLANE_STRIDE);       \
} while (0)

#define STEP_V(breg, ksi) do {                                                \
    __builtin_amdgcn_s_setprio(1);                                            \
    _Pragma("unroll")                                                         \
    for (int r = 0; r < 2; ++r) {                                             \
        short8 a1 = *(const short8*)&mk[aBase + r * 4096 + (ksi) * 512];      \
        _Pragma("unroll")                                                     \
        for (int j = 0; j < 3; ++j)                                           \
            acc[4 + j][r] = __builtin_amdgcn_mfma_f32_16x16x32_bf16(a1, breg[j], acc[4 + j][r], 0, 0, 0); \
    }                                                                         \
    __builtin_amdgcn_s_setprio(0);                                            \
} while (0)

// ---------------- main: 1024 threads = 16 waves (4 wr x 4 wc), 4 waves/SIMD ----
// Per wave: 32 rows x 16 cols -> acc[7][2] (56 regs). k-loop split into two passes
// (planes 0-3 then 4-6), each with the proven 2-slot B ping-pong, so peak live
// ~ acc56 + B32 + A16 + addr < 128-reg budget at 4 waves/SIMD.
__global__ __launch_bounds__(1024, 4) void main_kernel(
    const float* __restrict__ X, const unsigned short* __restrict__ Bt,
    const float* __restrict__ qtab, const float* __restrict__ logits,
    const float* __restrict__ bias, float* __restrict__ out)
{
    __shared__ unsigned short xs[BM * P_DIM];   // x_safe bf16, frag-ordered (64 KB)
    __shared__ unsigned short mk[BM * P_DIM];   // mask   bf16, frag-ordered (64 KB)
    __shared__ float pws[BM][3];                // softmax weights           (1.5 KB)

    const int tid = threadIdx.x;
    const int n0 = blockIdx.x * BM;
    const int lane = tid & 63;
    const int wid  = tid >> 6;     // 0..15
    const int l15  = lane & 15;
    const int lk   = lane >> 4;    // 0..3

    // ---- stage x tile: wave pair (wid>>1) owns rowblk, wid&1 owns ks-half ----
    {
        const int rowblk = wid >> 1;
        const int ksh    = (wid & 1) * 4;
        const float* Xb = X + (size_t)(n0 + rowblk * 16 + l15) * P_DIM + lk * 8;
        const int ebase = rowblk * 4096 + lk * 128 + l15 * 8;   // + ks*512
#pragma unroll
        for (int j = 0; j < 4; ++j) {
            int ks = ksh + j;
            floatx4 v0 = *(const floatx4*)(Xb + ks * 32);
            floatx4 v1 = *(const floatx4*)(Xb + ks * 32 + 4);
            unsigned int wx[4], wm[4];
#pragma unroll
            for (int h = 0; h < 2; ++h) {
                floatx4 v = h ? v1 : v0;
#pragma unroll
                for (int e = 0; e < 2; ++e) {
                    float f0 = v[2 * e], f1 = v[2 * e + 1];
                    bool na0 = !(f0 == f0), na1 = !(f1 == f1);
                    unsigned int s0 = na0 ? 0u : (unsigned int)f2bf(f0);
                    unsigned int s1 = na1 ? 0u : (unsigned int)f2bf(f1);
                    unsigned int m0 = na0 ? 0x3F80u : 0u;
                    unsigned int m1 = na1 ? 0x3F80u : 0u;
                    wx[h * 2 + e] = s0 | (s1 << 16);
                    wm[h * 2 + e] = m0 | (m1 << 16);
                }
            }
            uint4v px = {wx[0], wx[1], wx[2], wx[3]};
            uint4v pm = {wm[0], wm[1], wm[2], wm[3]};
            *(uint4v*)&xs[ebase + ks * 512] = px;
            *(uint4v*)&mk[ebase + ks * 512] = pm;
        }
    }

    // ---- fused loglik + softmax via q-tables: 8 threads per row -> pws[row][3] ----
    {
        int row = tid >> 3;
        int sub = tid & 7;
        const floatx4* xr = (const floatx4*)(X + (size_t)(n0 + row) * P_DIM);
        const floatx4* qt = (const floatx4*)qtab;
        float a0 = 0.f, a1 = 0.f, a2 = 0.f;
#pragma unroll
        for (int i = 0; i < 8; ++i) {
            floatx4 v = xr[sub * 8 + i];
#pragma unroll
            for (int e = 0; e < 4; ++e) {
                float x = v[e];
                int p = sub * 32 + i * 4 + e;
                bool valid = (x == x);
                float xv = valid ? x : 0.f;
                floatx4 qa = qt[p * 3 + 0];
                floatx4 qb = qt[p * 3 + 1];
                floatx4 qd = qt[p * 3 + 2];
                float q0 = fmaf(fmaf(qa[0], xv, qb[0]), xv, qd[0]);
                float q1 = fmaf(fmaf(qa[1], xv, qb[1]), xv, qd[1]);
                float q2 = fmaf(fmaf(qa[2], xv, qb[2]), xv, qd[2]);
                a0 += valid ? q0 : 0.f;
                a1 += valid ? q1 : 0.f;
                a2 += valid ? q2 : 0.f;
            }
        }
#pragma unroll
        for (int off = 1; off < 8; off <<= 1) {
            a0 += __shfl_xor(a0, off);
            a1 += __shfl_xor(a1, off);
            a2 += __shfl_xor(a2, off);
        }
        if (sub == 0) {
            float z0 = logits[0] - a0;
            float z1 = logits[1] - a1;
            float z2 = logits[2] - a2;
            float mx = fmaxf(z0, fmaxf(z1, z2));
            float e0 = __expf(z0 - mx), e1 = __expf(z1 - mx), e2 = __expf(z2 - mx);
            float inv = __builtin_amdgcn_rcpf(e0 + e1 + e2);
            pws[row][0] = e0 * inv;
            pws[row][1] = e1 * inv;
            pws[row][2] = e2 * inv;
        }
    }
    __syncthreads();

    // ---- persistent u-loop: two-pass 2-slot pipelined k-loop + expected_relu epilogue ----
    const int wr   = wid >> 2;     // 0..3 : 32-row slab
    const int wc   = wid & 3;      // 0..3 : 16-col group
    // frag r (rows wr*32 + r*16 + l15): rowblk = wr*2 + r
    const int aBase = wr * 8192 + lk * 128 + l15 * 8;     // + r*4096 + ks*512
    const int colk  = (wc * 16 + l15) * P_DIM + 8 * lk;   // per-lane elem offset in a u-tile plane
    const int phase = wc << 1;     // stagger: wc-groups at different u-phases (wr pack aligned)

#pragma unroll 1
    for (int ut0 = 0; ut0 < NUT; ++ut0) {
        const int ut = (ut0 + phase) & (NUT - 1);
        const unsigned short* bp = Bt + (size_t)ut * (BU * P_DIM) + colk;

        f32x4 acc[NPLANES][2];
#pragma unroll
        for (int pl = 0; pl < NPLANES; ++pl)
#pragma unroll
            for (int r = 0; r < 2; ++r)
                acc[pl][r] = (f32x4){0.f, 0.f, 0.f, 0.f};

        // pass A: mean planes 0..3
        {
            short8 bA[4], bB[4];
            LOADB_M(bA, 0);
#pragma unroll 1
            for (int ks = 0; ks < 8; ks += 2) {
                LOADB_M(bB, ks + 1);
                STEP_M(bA, ks);
                if (ks + 2 < 8) LOADB_M(bA, ks + 2);
                STEP_M(bB, ks + 1);
            }
        }
        // pass B: var planes 4..6
        {
            short8 bA[3], bB[3];
            LOADB_V(bA, 0);
#pragma unroll 1
            for (int ks = 0; ks < 8; ks += 2) {
                LOADB_V(bB, ks + 1);
                STEP_V(bA, ks);
                if (ks + 2 < 8) LOADB_V(bA, ks + 2);
                STEP_V(bB, ks + 1);
            }
        }

        // epilogue: D lane map col = lane&15, row = 4*(lane>>4)+q (+ r*16 + wr*32)
        const int ucol = ut * BU + wc * 16 + l15;
        const float bias_u = bias[ucol];
#pragma unroll
        for (int r = 0; r < 2; ++r) {
            int rloc = wr * 32 + r * 16 + 4 * lk;
#pragma unroll
            for (int q = 0; q < 4; ++q) {
                int rl = rloc + q;
                float p0 = pws[rl][0], p1 = pws[rl][1], p2 = pws[rl][2];
                float y0 = acc[0][r][q] + bias_u;
                float res = p0 * erl(y0 + acc[1][r][q], acc[4][r][q])
                          + p1 * erl(y0 + acc[2][r][q], acc[5][r][q])
                          + p2 * erl(y0 + acc[3][r][q], acc[6][r][q]);
                out[(size_t)(n0 + rl) * U_DIM + ucol] = res;
            }
        }
    }
}

extern "C" void kernel_launch(void* const* d_in, const int* in_sizes, int n_in,
                              void* d_out, int out_size, void* d_ws, size_t ws_size,
                              hipStream_t stream)
{
    const float* X      = (const float*)d_in[0];
    const float* cmeans = (const float*)d_in[1];
    const float* cvars  = (const float*)d_in[2];
    const float* logits = (const float*)d_in[3];
    const float* kern   = (const float*)d_in[4];
    const float* bias   = (const float*)d_in[5];
    float* out = (float*)d_out;

    char* wsb = (char*)d_ws;
    unsigned short* Bt = (unsigned short*)wsb;                 // 1,835,008 B
    float* qtab = (float*)(wsb + 1835008);                     //    12,288 B

    hipLaunchKernelGGL(prep_kernel, dim3(1794), dim3(512), 0, stream,
                       cmeans, cvars, kern, Bt, qtab);
    hipLaunchKernelGGL(main_kernel, dim3(N_ROWS / BM), dim3(1024), 0, stream,
                       X, Bt, qtab, logits, bias, out);
}

// Round 11
// 522.259 us; speedup vs baseline: 1.0447x; 1.0447x over previous
//
#include <hip/hip_runtime.h>
#include <hip/hip_bf16.h>
#include <math.h>

#define N_ROWS 65536
#define P_DIM  256
#define C_DIM  3
#define U_DIM  512
#define NPLANES 7
#define PLANE_STRIDE (U_DIM * P_DIM)   // 131072 elements per bf16 plane

#define BM 128
#define BU 64
#define NUT (U_DIM / BU)               // 8 u-tiles, persistent per block

typedef __attribute__((ext_vector_type(8))) short short8;     // 8 bf16 = 4 VGPR
typedef __attribute__((ext_vector_type(4))) float f32x4;
typedef __attribute__((ext_vector_type(4))) float floatx4;
typedef __attribute__((ext_vector_type(4))) unsigned int uint4v;

static __device__ __forceinline__ unsigned short f2bf(float f) {
    unsigned int u = __builtin_bit_cast(unsigned int, f);
    u += 0x7FFFu + ((u >> 16) & 1u);      // RNE
    return (unsigned short)(u >> 16);
}

// E[relu(N(m, v))]; exact relu when v == 0.
// Single-instruction rsq/rcp (1 ulp), Phi via Zelen-Severo poly reusing g = phi(w):
//   s*(g + w*Phi) = s*g + m*Phi ;  Phi(|w|) = 1 - g*poly(t), t = 1/(1+0.2316419|w|)
static __device__ __forceinline__ float erl(float m, float v) {
    float r = __builtin_amdgcn_rsqf(fmaxf(v, 1e-20f));
    float w = m * r;
    float s = v * r;
    float g = __expf(-0.5f * w * w) * 0.3989422804014327f;       // phi(w), even in w
    float aw = fabsf(w);
    float t = __builtin_amdgcn_rcpf(fmaf(0.2316419f, aw, 1.0f));
    float poly = t * (0.319381530f + t * (-0.356563782f + t * (1.781477937f
               + t * (-1.821255978f + t * 1.330274429f))));
    float Phi_pos = 1.0f - g * poly;
    float phi = (w >= 0.0f) ? Phi_pos : 1.0f - Phi_pos;
    float val = s * g + m * phi;
    return (v > 0.0f) ? val : fmaxf(m, 0.0f);
}

// ---------------- prep: build B planes (bf16, [plane][u][k] k-contiguous) + q-tables ----
// plane 0      : kernel[k][u]
// plane 1+c    : mu[k][c]   * kernel[k][u]
// plane 4+c    : var[k][c]  * kernel[k][u]^2
// qtab[p] = 3 float4: a_c = 1/(2v), b_c = -2 m a, d_c = m^2 a + 0.5 log(2 pi v)
__global__ __launch_bounds__(512) void prep_kernel(
    const float* __restrict__ cmeans, const float* __restrict__ cvars,
    const float* __restrict__ kern, unsigned short* __restrict__ Bt,
    float* __restrict__ qtab)
{
    int tid = blockIdx.x * 512 + threadIdx.x;
    const int TOTAL_B = NPLANES * PLANE_STRIDE;   // 917504
    if (tid < TOTAL_B) {
        int pl  = tid >> 17;
        int rem = tid & (PLANE_STRIDE - 1);
        int u   = rem >> 8;
        int k   = rem & (P_DIM - 1);
        float kv = kern[k * U_DIM + u];
        float val;
        if (pl == 0)      val = kv;
        else if (pl <= 3) val = cmeans[k * C_DIM + (pl - 1)] * kv;
        else              val = cvars[k * C_DIM + (pl - 4)] * (kv * kv);
        Bt[tid] = f2bf(val);
    } else if (tid - TOTAL_B < P_DIM) {
        int p = tid - TOTAL_B;
        float a[3], b[3], d[3];
#pragma unroll
        for (int c = 0; c < 3; ++c) {
            float m = cmeans[p * 3 + c];
            float v = cvars[p * 3 + c];
            float iv = 0.5f / v;
            a[c] = iv;
            b[c] = -2.0f * m * iv;
            d[c] = m * m * iv + 0.5f * logf(2.0f * 3.14159265359f * v);
        }
        float* q = qtab + p * 12;
        q[0] = a[0]; q[1] = a[1]; q[2]  = a[2]; q[3]  = 0.f;
        q[4] = b[0]; q[5] = b[1]; q[6]  = b[2]; q[7]  = 0.f;
        q[8] = d[0]; q[9] = d[1]; q[10] = d[2]; q[11] = 0.f;
    }
}

// load all 7 B-plane fragments for k-step ksi into the single buffer
#define LOADB(dst, ksi) do {                                                  \
    const unsigned short* _b = bp + (ksi) * 32;                               \
    _Pragma("unroll")                                                         \
    for (int pl = 0; pl < NPLANES; ++pl)                                      \
        dst[pl] = *(const short8*)(_b + (size_t)pl * PLANE_STRIDE);           \
} while (0)

// one k-step: 4 contiguous (conflict-free) LDS b128 reads + 14 MFMAs per r x 2
#define STEP(breg, ksi) do {                                                  \
    __builtin_amdgcn_s_setprio(1);                                            \
    _Pragma("unroll")                                                         \
    for (int r = 0; r < 2; ++r) {                                             \
        short8 a0 = *(const short8*)&xs[aBase + r * 4096 + (ksi) * 512];      \
        short8 a1 = *(const short8*)&mk[aBase + r * 4096 + (ksi) * 512];      \
        acc[0][r] = __builtin_amdgcn_mfma_f32_16x16x32_bf16(a0, breg[0], acc[0][r], 0, 0, 0); \
        _Pragma("unroll")                                                     \
        for (int pl = 1; pl < NPLANES; ++pl)                                  \
            acc[pl][r] = __builtin_amdgcn_mfma_f32_16x16x32_bf16(a1, breg[pl], acc[pl][r], 0, 0, 0); \
    }                                                                         \
    __builtin_amdgcn_s_setprio(0);                                            \
} while (0)

// ---------------- main: 1024 threads = 16 waves (4 wr x 4 wc), 4 waves/SIMD ----
// Per wave: 32 rows x 16 cols -> acc[7][2] (56, AGPR). Single-pass 7-plane k-step
// (28 MFMAs of cover), SINGLE B buffer (28 regs, no ping-pong): latency hiding via
// 4-wave TLP instead of software prefetch. Peak live ~ 56 acc + 28 B + 16 A + addr
// < 128-reg budget at 4 waves/SIMD.
__global__ __launch_bounds__(1024, 4) void main_kernel(
    const float* __restrict__ X, const unsigned short* __restrict__ Bt,
    const float* __restrict__ qtab, const float* __restrict__ logits,
    const float* __restrict__ bias, float* __restrict__ out)
{
    __shared__ unsigned short xs[BM * P_DIM];   // x_safe bf16, frag-ordered (64 KB)
    __shared__ unsigned short mk[BM * P_DIM];   // mask   bf16, frag-ordered (64 KB)
    __shared__ float pws[BM][3];                // softmax weights           (1.5 KB)

    const int tid = threadIdx.x;
    const int n0 = blockIdx.x * BM;
    const int lane = tid & 63;
    const int wid  = tid >> 6;     // 0..15
    const int l15  = lane & 15;
    const int lk   = lane >> 4;    // 0..3

    // ---- stage x tile: wave pair (wid>>1) owns rowblk, wid&1 owns ks-half ----
    {
        const int rowblk = wid >> 1;
        const int ksh    = (wid & 1) * 4;
        const float* Xb = X + (size_t)(n0 + rowblk * 16 + l15) * P_DIM + lk * 8;
        const int ebase = rowblk * 4096 + lk * 128 + l15 * 8;   // + ks*512
#pragma unroll
        for (int j = 0; j < 4; ++j) {
            int ks = ksh + j;
            floatx4 v0 = *(const floatx4*)(Xb + ks * 32);
            floatx4 v1 = *(const floatx4*)(Xb + ks * 32 + 4);
            unsigned int wx[4], wm[4];
#pragma unroll
            for (int h = 0; h < 2; ++h) {
                floatx4 v = h ? v1 : v0;
#pragma unroll
                for (int e = 0; e < 2; ++e) {
                    float f0 = v[2 * e], f1 = v[2 * e + 1];
                    bool na0 = !(f0 == f0), na1 = !(f1 == f1);
                    unsigned int s0 = na0 ? 0u : (unsigned int)f2bf(f0);
                    unsigned int s1 = na1 ? 0u : (unsigned int)f2bf(f1);
                    unsigned int m0 = na0 ? 0x3F80u : 0u;
                    unsigned int m1 = na1 ? 0x3F80u : 0u;
                    wx[h * 2 + e] = s0 | (s1 << 16);
                    wm[h * 2 + e] = m0 | (m1 << 16);
                }
            }
            uint4v px = {wx[0], wx[1], wx[2], wx[3]};
            uint4v pm = {wm[0], wm[1], wm[2], wm[3]};
            *(uint4v*)&xs[ebase + ks * 512] = px;
            *(uint4v*)&mk[ebase + ks * 512] = pm;
        }
    }

    // ---- fused loglik + softmax via q-tables: 8 threads per row -> pws[row][3] ----
    {
        int row = tid >> 3;
        int sub = tid & 7;
        const floatx4* xr = (const floatx4*)(X + (size_t)(n0 + row) * P_DIM);
        const floatx4* qt = (const floatx4*)qtab;
        float a0 = 0.f, a1 = 0.f, a2 = 0.f;
#pragma unroll
        for (int i = 0; i < 8; ++i) {
            floatx4 v = xr[sub * 8 + i];
#pragma unroll
            for (int e = 0; e < 4; ++e) {
                float x = v[e];
                int p = sub * 32 + i * 4 + e;
                bool valid = (x == x);
                float xv = valid ? x : 0.f;
                floatx4 qa = qt[p * 3 + 0];
                floatx4 qb = qt[p * 3 + 1];
                floatx4 qd = qt[p * 3 + 2];
                float q0 = fmaf(fmaf(qa[0], xv, qb[0]), xv, qd[0]);
                float q1 = fmaf(fmaf(qa[1], xv, qb[1]), xv, qd[1]);
                float q2 = fmaf(fmaf(qa[2], xv, qb[2]), xv, qd[2]);
                a0 += valid ? q0 : 0.f;
                a1 += valid ? q1 : 0.f;
                a2 += valid ? q2 : 0.f;
            }
        }
#pragma unroll
        for (int off = 1; off < 8; off <<= 1) {
            a0 += __shfl_xor(a0, off);
            a1 += __shfl_xor(a1, off);
            a2 += __shfl_xor(a2, off);
        }
        if (sub == 0) {
            float z0 = logits[0] - a0;
            float z1 = logits[1] - a1;
            float z2 = logits[2] - a2;
            float mx = fmaxf(z0, fmaxf(z1, z2));
            float e0 = __expf(z0 - mx), e1 = __expf(z1 - mx), e2 = __expf(z2 - mx);
            float inv = __builtin_amdgcn_rcpf(e0 + e1 + e2);
            pws[row][0] = e0 * inv;
            pws[row][1] = e1 * inv;
            pws[row][2] = e2 * inv;
        }
    }
    __syncthreads();

    // ---- persistent u-loop: single-buffer k-loop (TLP-hidden) + expected_relu epilogue ----
    const int wr   = wid >> 2;     // 0..3 : 32-row slab
    const int wc   = wid & 3;      // 0..3 : 16-col group
    // frag r (rows wr*32 + r*16 + l15): rowblk = wr*2 + r
    const int aBase = wr * 8192 + lk * 128 + l15 * 8;     // + r*4096 + ks*512
    const int colk  = (wc * 16 + l15) * P_DIM + 8 * lk;   // per-lane elem offset in a u-tile plane
    const int phase = wc << 1;     // stagger: wc-groups at different u-phases

#pragma unroll 1
    for (int ut0 = 0; ut0 < NUT; ++ut0) {
        const int ut = (ut0 + phase) & (NUT - 1);
        const unsigned short* bp = Bt + (size_t)ut * (BU * P_DIM) + colk;

        f32x4 acc[NPLANES][2];
#pragma unroll
        for (int pl = 0; pl < NPLANES; ++pl)
#pragma unroll
            for (int r = 0; r < 2; ++r)
                acc[pl][r] = (f32x4){0.f, 0.f, 0.f, 0.f};

        short8 bR[NPLANES];
#pragma unroll 1
        for (int ks = 0; ks < 8; ++ks) {
            LOADB(bR, ks);                        // issue 7 B loads
            __builtin_amdgcn_sched_barrier(0);    // keep loads above the MFMA cluster
            STEP(bR, ks);                         // 4 ds_reads + 28 MFMAs
        }

        // epilogue: D lane map col = lane&15, row = 4*(lane>>4)+q (+ r*16 + wr*32)
        const int ucol = ut * BU + wc * 16 + l15;
        const float bias_u = bias[ucol];
#pragma unroll
        for (int r = 0; r < 2; ++r) {
            int rloc = wr * 32 + r * 16 + 4 * lk;
#pragma unroll
            for (int q = 0; q < 4; ++q) {
                int rl = rloc + q;
                float p0 = pws[rl][0], p1 = pws[rl][1], p2 = pws[rl][2];
                float y0 = acc[0][r][q] + bias_u;
                float res = p0 * erl(y0 + acc[1][r][q], acc[4][r][q])
                          + p1 * erl(y0 + acc[2][r][q], acc[5][r][q])
                          + p2 * erl(y0 + acc[3][r][q], acc[6][r][q]);
                out[(size_t)(n0 + rl) * U_DIM + ucol] = res;
            }
        }
    }
}

extern "C" void kernel_launch(void* const* d_in, const int* in_sizes, int n_in,
                              void* d_out, int out_size, void* d_ws, size_t ws_size,
                              hipStream_t stream)
{
    const float* X      = (const float*)d_in[0];
    const float* cmeans = (const float*)d_in[1];
    const float* cvars  = (const float*)d_in[2];
    const float* logits = (const float*)d_in[3];
    const float* kern   = (const float*)d_in[4];
    const float* bias   = (const float*)d_in[5];
    float* out = (float*)d_out;

    char* wsb = (char*)d_ws;
    unsigned short* Bt = (unsigned short*)wsb;                 // 1,835,008 B
    float* qtab = (float*)(wsb + 1835008);                     //    12,288 B

    hipLaunchKernelGGL(prep_kernel, dim3(1794), dim3(512), 0, stream,
                       cmeans, cvars, kern, Bt, qtab);
    hipLaunchKernelGGL(main_kernel, dim3(N_ROWS / BM), dim3(1024), 0, stream,
                       X, Bt, qtab, logits, bias, out);
}

// Round 12
// 286.605 us; speedup vs baseline: 1.9037x; 1.8222x over previous
//
#include <hip/hip_runtime.h>
#include <hip/hip_bf16.h>
#include <math.h>

#define N_ROWS 65536
#define P_DIM  256
#define C_DIM  3
#define U_DIM  512
#define NPLANES 7
#define PLANE_STRIDE (U_DIM * P_DIM)   // 131072 elements per bf16 plane

#define BM 128
#define BU 64
#define NUT (U_DIM / BU)               // 8 u-tiles, persistent per block

typedef __attribute__((ext_vector_type(8))) short short8;     // 8 bf16 = 4 VGPR
typedef __attribute__((ext_vector_type(4))) float f32x4;
typedef __attribute__((ext_vector_type(4))) float floatx4;
typedef __attribute__((ext_vector_type(4))) unsigned int uint4v;

static __device__ __forceinline__ unsigned short f2bf(float f) {
    unsigned int u = __builtin_bit_cast(unsigned int, f);
    u += 0x7FFFu + ((u >> 16) & 1u);      // RNE
    return (unsigned short)(u >> 16);
}

// E[relu(N(m, v))]; exact relu when v == 0.
// Single-instruction rsq/rcp (1 ulp), Phi via Zelen-Severo poly reusing g = phi(w):
//   s*(g + w*Phi) = s*g + m*Phi ;  Phi(|w|) = 1 - g*poly(t), t = 1/(1+0.2316419|w|)
static __device__ __forceinline__ float erl(float m, float v) {
    float r = __builtin_amdgcn_rsqf(fmaxf(v, 1e-20f));
    float w = m * r;
    float s = v * r;
    float g = __expf(-0.5f * w * w) * 0.3989422804014327f;       // phi(w), even in w
    float aw = fabsf(w);
    float t = __builtin_amdgcn_rcpf(fmaf(0.2316419f, aw, 1.0f));
    float poly = t * (0.319381530f + t * (-0.356563782f + t * (1.781477937f
               + t * (-1.821255978f + t * 1.330274429f))));
    float Phi_pos = 1.0f - g * poly;
    float phi = (w >= 0.0f) ? Phi_pos : 1.0f - Phi_pos;
    float val = s * g + m * phi;
    return (v > 0.0f) ? val : fmaxf(m, 0.0f);
}

// ---------------- prep: fragment-packed B + q-tables ----------------
// Bf[ut][wc][ks][pl][lane][e]: the exact 1KB a wave reads per (ut,wc,ks,pl) is
// CONTIGUOUS (addr = base + lane*16B) -> 8 cache lines per load inst, not 64.
//   u = ut*64 + wc*16 + (lane&15);  k = ks*32 + (lane>>4)*8 + e
// plane 0: kernel[k][u]; 1+c: mu[k][c]*kernel; 4+c: var[k][c]*kernel^2
// qtab[p] = 3 float4: a_c = 1/(2v), b_c = -2 m a, d_c = m^2 a + 0.5 log(2 pi v)
__global__ __launch_bounds__(512) void prep_kernel(
    const float* __restrict__ cmeans, const float* __restrict__ cvars,
    const float* __restrict__ kern, unsigned short* __restrict__ Bf,
    float* __restrict__ qtab)
{
    int tid = blockIdx.x * 512 + threadIdx.x;
    const int TOTAL_B = NPLANES * PLANE_STRIDE;   // 917504
    if (tid < TOTAL_B) {
        int e    = tid & 7;
        int lane = (tid >> 3) & 63;
        int rest = tid >> 9;          // 0..1791
        int pl   = rest % 7;
        int rk   = rest / 7;          // 0..255
        int ks   = rk & 7;
        int uw   = rk >> 3;           // 0..31
        int wc   = uw & 3;
        int ut   = uw >> 2;
        int u = ut * 64 + wc * 16 + (lane & 15);
        int k = ks * 32 + (lane >> 4) * 8 + e;
        float kv = kern[k * U_DIM + u];
        float val;
        if (pl == 0)      val = kv;
        else if (pl <= 3) val = cmeans[k * C_DIM + (pl - 1)] * kv;
        else              val = cvars[k * C_DIM + (pl - 4)] * (kv * kv);
        Bf[tid] = f2bf(val);
    } else if (tid - TOTAL_B < P_DIM) {
        int p = tid - TOTAL_B;
        float a[3], b[3], d[3];
#pragma unroll
        for (int c = 0; c < 3; ++c) {
            float m = cmeans[p * 3 + c];
            float v = cvars[p * 3 + c];
            float iv = 0.5f / v;
            a[c] = iv;
            b[c] = -2.0f * m * iv;
            d[c] = m * m * iv + 0.5f * logf(2.0f * 3.14159265359f * v);
        }
        float* q = qtab + p * 12;
        q[0] = a[0]; q[1] = a[1]; q[2]  = a[2]; q[3]  = 0.f;
        q[4] = b[0]; q[5] = b[1]; q[6]  = b[2]; q[7]  = 0.f;
        q[8] = d[0]; q[9] = d[1]; q[10] = d[2]; q[11] = 0.f;
    }
}

// load 7 B-plane fragments for k-step ksi into slot regs (coalesced 1KB blocks)
#define LOADB(dst, ksi) do {                                                  \
    _Pragma("unroll")                                                         \
    for (int pl = 0; pl < NPLANES; ++pl)                                      \
        dst[pl] = *(const short8*)(bpw + ((ksi) * 7 + pl) * 512);             \
} while (0)

// one k-step: 8 contiguous (conflict-free) LDS A-reads + 28 MFMAs using B slot `breg`
// fragment-ordered LDS layout: elem = rowblk*4096 + ks*512 + lk*128 + r16*8
#define STEP(breg, ksi) do {                                                  \
    __builtin_amdgcn_s_setprio(1);                                            \
    _Pragma("unroll")                                                         \
    for (int r = 0; r < 4; ++r) {                                             \
        short8 a0 = *(const short8*)&xs[aBase + r * 4096 + (ksi) * 512];      \
        short8 a1 = *(const short8*)&mk[aBase + r * 4096 + (ksi) * 512];      \
        acc[0][r] = __builtin_amdgcn_mfma_f32_16x16x32_bf16(a0, breg[0], acc[0][r], 0, 0, 0); \
        _Pragma("unroll")                                                     \
        for (int pl = 1; pl < NPLANES; ++pl)                                  \
            acc[pl][r] = __builtin_amdgcn_mfma_f32_16x16x32_bf16(a1, breg[pl], acc[pl][r], 0, 0, 0); \
    }                                                                         \
    __builtin_amdgcn_s_setprio(0);                                            \
} while (0)

// ---------------- main: stage X once, fused loglik+softmax, 8 persistent u-tiles ----
// 512 threads = 8 waves (2 row-halves x 4 col-groups); each wave: 64 rows x 16 cols.
// 2-slot B ping-pong (proven no-spill). Barrier-free u-loop with wc-phase stagger.
__global__ __launch_bounds__(512, 2) void main_kernel(
    const float* __restrict__ X, const unsigned short* __restrict__ Bf,
    const float* __restrict__ qtab, const float* __restrict__ logits,
    const float* __restrict__ bias, float* __restrict__ out)
{
    __shared__ unsigned short xs[BM * P_DIM];   // x_safe bf16, frag-ordered (64 KB)
    __shared__ unsigned short mk[BM * P_DIM];   // mask   bf16, frag-ordered (64 KB)
    __shared__ float pws[BM][3];                // softmax weights           (1.5 KB)

    const int tid = threadIdx.x;
    const int n0 = blockIdx.x * BM;
    const int lane = tid & 63;
    const int wid  = tid >> 6;     // 0..7
    const int l15  = lane & 15;
    const int lk   = lane >> 4;    // 0..3

    // ---- stage x tile: wave wid owns rowblk=wid (16 rows); lane=(r16,lk) reads
    // float8 at [row=wid*16+l15][k=ks*32+lk*8]; LDS writes contiguous 16B/lane ----
    {
        const float* Xb = X + (size_t)(n0 + wid * 16 + l15) * P_DIM + lk * 8;
        const int ebase = wid * 4096 + lk * 128 + l15 * 8;   // + ks*512
#pragma unroll
        for (int ks = 0; ks < 8; ++ks) {
            floatx4 v0 = *(const floatx4*)(Xb + ks * 32);
            floatx4 v1 = *(const floatx4*)(Xb + ks * 32 + 4);
            unsigned int wx[4], wm[4];
#pragma unroll
            for (int h = 0; h < 2; ++h) {
                floatx4 v = h ? v1 : v0;
#pragma unroll
                for (int e = 0; e < 2; ++e) {
                    float f0 = v[2 * e], f1 = v[2 * e + 1];
                    bool na0 = !(f0 == f0), na1 = !(f1 == f1);
                    unsigned int s0 = na0 ? 0u : (unsigned int)f2bf(f0);
                    unsigned int s1 = na1 ? 0u : (unsigned int)f2bf(f1);
                    unsigned int m0 = na0 ? 0x3F80u : 0u;
                    unsigned int m1 = na1 ? 0x3F80u : 0u;
                    wx[h * 2 + e] = s0 | (s1 << 16);
                    wm[h * 2 + e] = m0 | (m1 << 16);
                }
            }
            uint4v px = {wx[0], wx[1], wx[2], wx[3]};
            uint4v pm = {wm[0], wm[1], wm[2], wm[3]};
            *(uint4v*)&xs[ebase + ks * 512] = px;
            *(uint4v*)&mk[ebase + ks * 512] = pm;
        }
    }

    // ---- fused loglik + softmax via q-tables: 4 threads per row -> pws[row][3] ----
    {
        int row = tid >> 2;
        int sub = tid & 3;
        const floatx4* xr = (const floatx4*)(X + (size_t)(n0 + row) * P_DIM);
        const floatx4* qt = (const floatx4*)qtab;
        float a0 = 0.f, a1 = 0.f, a2 = 0.f;
#pragma unroll
        for (int i = 0; i < 16; ++i) {
            floatx4 v = xr[sub * 16 + i];
#pragma unroll
            for (int e = 0; e < 4; ++e) {
                float x = v[e];
                int p = sub * 64 + i * 4 + e;
                bool valid = (x == x);
                float xv = valid ? x : 0.f;
                floatx4 qa = qt[p * 3 + 0];
                floatx4 qb = qt[p * 3 + 1];
                floatx4 qd = qt[p * 3 + 2];
                float q0 = fmaf(fmaf(qa[0], xv, qb[0]), xv, qd[0]);
                float q1 = fmaf(fmaf(qa[1], xv, qb[1]), xv, qd[1]);
                float q2 = fmaf(fmaf(qa[2], xv, qb[2]), xv, qd[2]);
                a0 += valid ? q0 : 0.f;
                a1 += valid ? q1 : 0.f;
                a2 += valid ? q2 : 0.f;
            }
        }
#pragma unroll
        for (int off = 1; off < 4; off <<= 1) {
            a0 += __shfl_xor(a0, off);
            a1 += __shfl_xor(a1, off);
            a2 += __shfl_xor(a2, off);
        }
        if (sub == 0) {
            float z0 = logits[0] - a0;
            float z1 = logits[1] - a1;
            float z2 = logits[2] - a2;
            float mx = fmaxf(z0, fmaxf(z1, z2));
            float e0 = __expf(z0 - mx), e1 = __expf(z1 - mx), e2 = __expf(z2 - mx);
            float inv = __builtin_amdgcn_rcpf(e0 + e1 + e2);
            pws[row][0] = e0 * inv;
            pws[row][1] = e1 * inv;
            pws[row][2] = e2 * inv;
        }
    }
    __syncthreads();

    // ---- persistent u-loop: 2-slot pipelined k-loop MFMA + expected_relu epilogue ----
    const int wr   = wid >> 2;     // 0..1 : 64-row half
    const int wc   = wid & 3;      // 0..3 : 16-col group
    // frag r (rows wr*64 + r*16 + l15): rowblk = wr*4 + r
    const int aBase = wr * 16384 + lk * 128 + l15 * 8;    // + r*4096 + ks*512
    const int phase = wc << 1;     // stagger: wc-groups at different u-phases

#pragma unroll 1
    for (int ut0 = 0; ut0 < NUT; ++ut0) {
        const int ut = (ut0 + phase) & (NUT - 1);
        // coalesced fragment base: Bf[ut][wc][.][.][lane][.]
        const unsigned short* bpw = Bf + ((size_t)(ut * 4 + wc) * (8 * 7 * 512)) + (size_t)lane * 8;

        f32x4 acc[NPLANES][4];
#pragma unroll
        for (int pl = 0; pl < NPLANES; ++pl)
#pragma unroll
            for (int r = 0; r < 4; ++r)
                acc[pl][r] = (f32x4){0.f, 0.f, 0.f, 0.f};

        short8 bA[NPLANES], bB[NPLANES];
        LOADB(bA, 0);
#pragma unroll 1
        for (int ks = 0; ks < 8; ks += 2) {
            LOADB(bB, ks + 1);          // prefetch odd step
            STEP(bA, ks);               // compute even step
            if (ks + 2 < 8) LOADB(bA, ks + 2);   // prefetch next even step
            STEP(bB, ks + 1);           // compute odd step
        }

        // epilogue: D lane map col = lane&15, row = 4*(lane>>4)+q (+ r*16 + wr*64)
        const int ucol = ut * BU + wc * 16 + l15;
        const float bias_u = bias[ucol];
#pragma unroll
        for (int r = 0; r < 4; ++r) {
            int rloc = wr * 64 + r * 16 + 4 * lk;
#pragma unroll
            for (int q = 0; q < 4; ++q) {
                int rl = rloc + q;
                float p0 = pws[rl][0], p1 = pws[rl][1], p2 = pws[rl][2];
                float y0 = acc[0][r][q] + bias_u;
                float res = p0 * erl(y0 + acc[1][r][q], acc[4][r][q])
                          + p1 * erl(y0 + acc[2][r][q], acc[5][r][q])
                          + p2 * erl(y0 + acc[3][r][q], acc[6][r][q]);
                out[(size_t)(n0 + rl) * U_DIM + ucol] = res;
            }
        }
    }
}

extern "C" void kernel_launch(void* const* d_in, const int* in_sizes, int n_in,
                              void* d_out, int out_size, void* d_ws, size_t ws_size,
                              hipStream_t stream)
{
    const float* X      = (const float*)d_in[0];
    const float* cmeans = (const float*)d_in[1];
    const float* cvars  = (const float*)d_in[2];
    const float* logits = (const float*)d_in[3];
    const float* kern   = (const float*)d_in[4];
    const float* bias   = (const float*)d_in[5];
    float* out = (float*)d_out;

    char* wsb = (char*)d_ws;
    unsigned short* Bf = (unsigned short*)wsb;                 // 1,835,008 B
    float* qtab = (float*)(wsb + 1835008);                     //    12,288 B

    hipLaunchKernelGGL(prep_kernel, dim3(1794), dim3(512), 0, stream,
                       cmeans, cvars, kern, Bf, qtab);
    hipLaunchKernelGGL(main_kernel, dim3(N_ROWS / BM), dim3(512), 0, stream,
                       X, Bf, qtab, logits, bias, out);
}

// Round 13
// 272.247 us; speedup vs baseline: 2.0041x; 1.0527x over previous
//
#include <hip/hip_runtime.h>
#include <hip/hip_bf16.h>
#include <math.h>

#define N_ROWS 65536
#define P_DIM  256
#define C_DIM  3
#define U_DIM  512
#define NPLANES 7

#define BM 128
#define BU 64
#define NUT (U_DIM / BU)               // 8 u-tiles, persistent per block

typedef __attribute__((ext_vector_type(8))) short short8;     // 8 bf16 = 4 VGPR
typedef __attribute__((ext_vector_type(4))) float f32x4;
typedef __attribute__((ext_vector_type(4))) float floatx4;
typedef __attribute__((ext_vector_type(4))) unsigned int uint4v;

static __device__ __forceinline__ unsigned short f2bf(float f) {
    unsigned int u = __builtin_bit_cast(unsigned int, f);
    u += 0x7FFFu + ((u >> 16) & 1u);      // RNE
    return (unsigned short)(u >> 16);
}

// E[relu(N(m, v))]; exact relu when v == 0.
// Single-instruction rsq/rcp (1 ulp), Phi via Zelen-Severo poly reusing g = phi(w):
//   s*(g + w*Phi) = s*g + m*Phi ;  Phi(|w|) = 1 - g*poly(t), t = 1/(1+0.2316419|w|)
static __device__ __forceinline__ float erl(float m, float v) {
    float r = __builtin_amdgcn_rsqf(fmaxf(v, 1e-20f));
    float w = m * r;
    float s = v * r;
    float g = __expf(-0.5f * w * w) * 0.3989422804014327f;       // phi(w), even in w
    float aw = fabsf(w);
    float t = __builtin_amdgcn_rcpf(fmaf(0.2316419f, aw, 1.0f));
    float poly = t * (0.319381530f + t * (-0.356563782f + t * (1.781477937f
               + t * (-1.821255978f + t * 1.330274429f))));
    float Phi_pos = 1.0f - g * poly;
    float phi = (w >= 0.0f) ? Phi_pos : 1.0f - Phi_pos;
    float val = s * g + m * phi;
    return (v > 0.0f) ? val : fmaxf(m, 0.0f);
}

// ---------------- prep: fragment-packed B + q-tables ----------------
// Bf[ut][wc][ks][pl][lane][e]: the exact 1KB a wave reads per (ut,wc,ks,pl) is
// CONTIGUOUS (addr = base + lane*16B) -> 8 cache lines per load inst, not 64.
//   u = ut*64 + wc*16 + (lane&15);  k = ks*32 + (lane>>4)*8 + e
// plane 0: kernel[k][u]; 1+c: mu[k][c]*kernel; 4+c: var[k][c]*kernel^2
// qtab[p] = 3 float4: a_c = 1/(2v), b_c = -2 m a, d_c = m^2 a + 0.5 log(2 pi v)
__global__ __launch_bounds__(512) void prep_kernel(
    const float* __restrict__ cmeans, const float* __restrict__ cvars,
    const float* __restrict__ kern, unsigned short* __restrict__ Bf,
    float* __restrict__ qtab)
{
    int tid = blockIdx.x * 512 + threadIdx.x;
    const int TOTAL_B = NPLANES * U_DIM * P_DIM;   // 917504
    if (tid < TOTAL_B) {
        int e    = tid & 7;
        int lane = (tid >> 3) & 63;
        int rest = tid >> 9;          // 0..1791
        int pl   = rest % 7;
        int rk   = rest / 7;          // 0..255
        int ks   = rk & 7;
        int uw   = rk >> 3;           // 0..31
        int wc   = uw & 3;
        int ut   = uw >> 2;
        int u = ut * 64 + wc * 16 + (lane & 15);
        int k = ks * 32 + (lane >> 4) * 8 + e;
        float kv = kern[k * U_DIM + u];
        float val;
        if (pl == 0)      val = kv;
        else if (pl <= 3) val = cmeans[k * C_DIM + (pl - 1)] * kv;
        else              val = cvars[k * C_DIM + (pl - 4)] * (kv * kv);
        Bf[tid] = f2bf(val);
    } else if (tid - TOTAL_B < P_DIM) {
        int p = tid - TOTAL_B;
        float a[3], b[3], d[3];
#pragma unroll
        for (int c = 0; c < 3; ++c) {
            float m = cmeans[p * 3 + c];
            float v = cvars[p * 3 + c];
            float iv = 0.5f / v;
            a[c] = iv;
            b[c] = -2.0f * m * iv;
            d[c] = m * m * iv + 0.5f * logf(2.0f * 3.14159265359f * v);
        }
        float* q = qtab + p * 12;
        q[0] = a[0]; q[1] = a[1]; q[2]  = a[2]; q[3]  = 0.f;
        q[4] = b[0]; q[5] = b[1]; q[6]  = b[2]; q[7]  = 0.f;
        q[8] = d[0]; q[9] = d[1]; q[10] = d[2]; q[11] = 0.f;
    }
}

// load 7 B-plane fragments for k-step ksi into the single buffer (coalesced 1KB blocks)
#define LOADB(dst, ksi) do {                                                  \
    _Pragma("unroll")                                                         \
    for (int pl = 0; pl < NPLANES; ++pl)                                      \
        dst[pl] = *(const short8*)(bpw + ((ksi) * 7 + pl) * 512);             \
} while (0)

// one k-step: 4 contiguous (conflict-free) LDS A-reads + 14 MFMAs per r, r<2
// fragment-ordered LDS layout: elem = rowblk*4096 + ks*512 + lk*128 + r16*8
#define STEP(breg, ksi) do {                                                  \
    __builtin_amdgcn_s_setprio(1);                                            \
    _Pragma("unroll")                                                         \
    for (int r = 0; r < 2; ++r) {                                             \
        short8 a0 = *(const short8*)&xs[aBase + r * 4096 + (ksi) * 512];      \
        short8 a1 = *(const short8*)&mk[aBase + r * 4096 + (ksi) * 512];      \
        acc[0][r] = __builtin_amdgcn_mfma_f32_16x16x32_bf16(a0, breg[0], acc[0][r], 0, 0, 0); \
        _Pragma("unroll")                                                     \
        for (int pl = 1; pl < NPLANES; ++pl)                                  \
            acc[pl][r] = __builtin_amdgcn_mfma_f32_16x16x32_bf16(a1, breg[pl], acc[pl][r], 0, 0, 0); \
    }                                                                         \
    __builtin_amdgcn_s_setprio(0);                                            \
} while (0)

// ---------------- main: 1024 threads = 16 waves (4 wr x 4 wc), 4 waves/SIMD ----
// Per wave: 32 rows x 16 cols -> acc[7][2] (56, AGPR). Single-pass 7-plane k-step
// (28 MFMAs of cover), SINGLE packed-B buffer (28 regs): distance-0 loads hidden by
// 4-wave TLP (duty cycle ~136/(300+136) x 4 waves > 1 -> matrix pipe saturates).
// Peak live ~ 56 acc + 28 B + 16 A + addr < 128-reg budget at 4 waves/SIMD.
__global__ __launch_bounds__(1024, 4) void main_kernel(
    const float* __restrict__ X, const unsigned short* __restrict__ Bf,
    const float* __restrict__ qtab, const float* __restrict__ logits,
    const float* __restrict__ bias, float* __restrict__ out)
{
    __shared__ unsigned short xs[BM * P_DIM];   // x_safe bf16, frag-ordered (64 KB)
    __shared__ unsigned short mk[BM * P_DIM];   // mask   bf16, frag-ordered (64 KB)
    __shared__ float pws[BM][3];                // softmax weights           (1.5 KB)

    const int tid = threadIdx.x;
    const int n0 = blockIdx.x * BM;
    const int lane = tid & 63;
    const int wid  = tid >> 6;     // 0..15
    const int l15  = lane & 15;
    const int lk   = lane >> 4;    // 0..3

    // ---- stage x tile: wave pair (wid>>1) owns rowblk, wid&1 owns ks-half ----
    {
        const int rowblk = wid >> 1;
        const int ksh    = (wid & 1) * 4;
        const float* Xb = X + (size_t)(n0 + rowblk * 16 + l15) * P_DIM + lk * 8;
        const int ebase = rowblk * 4096 + lk * 128 + l15 * 8;   // + ks*512
#pragma unroll
        for (int j = 0; j < 4; ++j) {
            int ks = ksh + j;
            floatx4 v0 = *(const floatx4*)(Xb + ks * 32);
            floatx4 v1 = *(const floatx4*)(Xb + ks * 32 + 4);
            unsigned int wx[4], wm[4];
#pragma unroll
            for (int h = 0; h < 2; ++h) {
                floatx4 v = h ? v1 : v0;
#pragma unroll
                for (int e = 0; e < 2; ++e) {
                    float f0 = v[2 * e], f1 = v[2 * e + 1];
                    bool na0 = !(f0 == f0), na1 = !(f1 == f1);
                    unsigned int s0 = na0 ? 0u : (unsigned int)f2bf(f0);
                    unsigned int s1 = na1 ? 0u : (unsigned int)f2bf(f1);
                    unsigned int m0 = na0 ? 0x3F80u : 0u;
                    unsigned int m1 = na1 ? 0x3F80u : 0u;
                    wx[h * 2 + e] = s0 | (s1 << 16);
                    wm[h * 2 + e] = m0 | (m1 << 16);
                }
            }
            uint4v px = {wx[0], wx[1], wx[2], wx[3]};
            uint4v pm = {wm[0], wm[1], wm[2], wm[3]};
            *(uint4v*)&xs[ebase + ks * 512] = px;
            *(uint4v*)&mk[ebase + ks * 512] = pm;
        }
    }

    // ---- fused loglik + softmax via q-tables: 8 threads per row -> pws[row][3] ----
    {
        int row = tid >> 3;
        int sub = tid & 7;
        const floatx4* xr = (const floatx4*)(X + (size_t)(n0 + row) * P_DIM);
        const floatx4* qt = (const floatx4*)qtab;
        float a0 = 0.f, a1 = 0.f, a2 = 0.f;
#pragma unroll
        for (int i = 0; i < 8; ++i) {
            floatx4 v = xr[sub * 8 + i];
#pragma unroll
            for (int e = 0; e < 4; ++e) {
                float x = v[e];
                int p = sub * 32 + i * 4 + e;
                bool valid = (x == x);
                float xv = valid ? x : 0.f;
                floatx4 qa = qt[p * 3 + 0];
                floatx4 qb = qt[p * 3 + 1];
                floatx4 qd = qt[p * 3 + 2];
                float q0 = fmaf(fmaf(qa[0], xv, qb[0]), xv, qd[0]);
                float q1 = fmaf(fmaf(qa[1], xv, qb[1]), xv, qd[1]);
                float q2 = fmaf(fmaf(qa[2], xv, qb[2]), xv, qd[2]);
                a0 += valid ? q0 : 0.f;
                a1 += valid ? q1 : 0.f;
                a2 += valid ? q2 : 0.f;
            }
        }
#pragma unroll
        for (int off = 1; off < 8; off <<= 1) {
            a0 += __shfl_xor(a0, off);
            a1 += __shfl_xor(a1, off);
            a2 += __shfl_xor(a2, off);
        }
        if (sub == 0) {
            float z0 = logits[0] - a0;
            float z1 = logits[1] - a1;
            float z2 = logits[2] - a2;
            float mx = fmaxf(z0, fmaxf(z1, z2));
            float e0 = __expf(z0 - mx), e1 = __expf(z1 - mx), e2 = __expf(z2 - mx);
            float inv = __builtin_amdgcn_rcpf(e0 + e1 + e2);
            pws[row][0] = e0 * inv;
            pws[row][1] = e1 * inv;
            pws[row][2] = e2 * inv;
        }
    }
    __syncthreads();

    // ---- persistent u-loop: single-buffer packed-B k-loop + expected_relu epilogue ----
    const int wr   = wid >> 2;     // 0..3 : 32-row slab
    const int wc   = wid & 3;      // 0..3 : 16-col group
    // frag r (rows wr*32 + r*16 + l15): rowblk = wr*2 + r
    const int aBase = wr * 8192 + lk * 128 + l15 * 8;     // + r*4096 + ks*512
    const int phase = wc << 1;     // stagger: wc-groups at different u-phases

#pragma unroll 1
    for (int ut0 = 0; ut0 < NUT; ++ut0) {
        const int ut = (ut0 + phase) & (NUT - 1);
        // coalesced fragment base: Bf[ut][wc][.][.][lane][.]
        const unsigned short* bpw = Bf + ((size_t)(ut * 4 + wc) * (8 * 7 * 512)) + (size_t)lane * 8;

        f32x4 acc[NPLANES][2];
#pragma unroll
        for (int pl = 0; pl < NPLANES; ++pl)
#pragma unroll
            for (int r = 0; r < 2; ++r)
                acc[pl][r] = (f32x4){0.f, 0.f, 0.f, 0.f};

        short8 bR[NPLANES];
#pragma unroll 1
        for (int ks = 0; ks < 8; ++ks) {
            LOADB(bR, ks);                        // issue 7 coalesced 1KB loads
            __builtin_amdgcn_sched_barrier(0);    // keep loads above the MFMA cluster
            STEP(bR, ks);                         // 4 ds_reads + 28 MFMAs
        }

        // epilogue: D lane map col = lane&15, row = 4*(lane>>4)+q (+ r*16 + wr*32)
        const int ucol = ut * BU + wc * 16 + l15;
        const float bias_u = bias[ucol];
#pragma unroll
        for (int r = 0; r < 2; ++r) {
            int rloc = wr * 32 + r * 16 + 4 * lk;
#pragma unroll
            for (int q = 0; q < 4; ++q) {
                int rl = rloc + q;
                float p0 = pws[rl][0], p1 = pws[rl][1], p2 = pws[rl][2];
                float y0 = acc[0][r][q] + bias_u;
                float res = p0 * erl(y0 + acc[1][r][q], acc[4][r][q])
                          + p1 * erl(y0 + acc[2][r][q], acc[5][r][q])
                          + p2 * erl(y0 + acc[3][r][q], acc[6][r][q]);
                out[(size_t)(n0 + rl) * U_DIM + ucol] = res;
            }
        }
    }
}

extern "C" void kernel_launch(void* const* d_in, const int* in_sizes, int n_in,
                              void* d_out, int out_size, void* d_ws, size_t ws_size,
                              hipStream_t stream)
{
    const float* X      = (const float*)d_in[0];
    const float* cmeans = (const float*)d_in[1];
    const float* cvars  = (const float*)d_in[2];
    const float* logits = (const float*)d_in[3];
    const float* kern   = (const float*)d_in[4];
    const float* bias   = (const float*)d_in[5];
    float* out = (float*)d_out;

    char* wsb = (char*)d_ws;
    unsigned short* Bf = (unsigned short*)wsb;                 // 1,835,008 B
    float* qtab = (float*)(wsb + 1835008);                     //    12,288 B

    hipLaunchKernelGGL(prep_kernel, dim3(1794), dim3(512), 0, stream,
                       cmeans, cvars, kern, Bf, qtab);
    hipLaunchKernelGGL(main_kernel, dim3(N_ROWS / BM), dim3(1024), 0, stream,
                       X, Bf, qtab, logits, bias, out);
}